// Round 4
// baseline (284.591 us; speedup 1.0000x reference)
//
#include <hip/hip_runtime.h>
#include <math.h>

#define NQ  12
#define TPB 64

// ================= compile-time GF(2) machinery =================
// Physical index space x = CNOT-folded storage space (validated r1/r3):
// gate on qubit q in layer l pairs x <-> x^v (v = col b of Minv_l, b=11-q),
// role = parity(r & x) (r = row b of M_l).
// Radix-64: 8 passes x 6 gates. Per-pass layout L_p: rows 0..5 = r_j
// (role = logical addr bit j, L_p v_j = e_j), rows 6..11 = basis of the
// annihilator of span{v_j} = rows of M_l for the other 6 bits (duality!).
// Thread t owns logical addrs a = z | t<<6 (z = 0..63 register slots).
// LDS elem (float2) index E = sigma(a) = a ^ ((a>>6 & 7)<<1): contiguous
// b128 reads are bank-conflict-free. Transition write: E' = sigma(L_{p+1}
// L_p^{-1} a); rows 6..8 of L_{p+1} are re-chosen (within the annihilator,
// constexpr greedy) so lane bits map rank-4 onto LDS bank-pairs -> writes
// conflict-free too.

struct GF12 { unsigned row[12]; };

constexpr GF12 gf_id(){ GF12 m{}; for(int i=0;i<12;i++) m.row[i]=1u<<i; return m; }
constexpr GF12 gf_mul(const GF12&A,const GF12&B){
  GF12 r{};
  for(int i=0;i<12;i++){ unsigned acc=0;
    for(int k=0;k<12;k++) if((A.row[i]>>k)&1u) acc ^= B.row[k];
    r.row[i]=acc; }
  return r;
}
constexpr unsigned gf_apply(const GF12&A, unsigned x){
  unsigned y=0;
  for(int i=0;i<12;i++) y |= (unsigned)(__builtin_popcount(A.row[i]&x)&1)<<i;
  return y;
}
constexpr GF12 gf_cnot(int q){ GF12 m=gf_id(); int c=11-q, t=11-((q+1)%12); m.row[t]^=(1u<<c); return m; }
constexpr GF12 gf_inv(const GF12&A){
  unsigned a[12], inv[12];
  for(int i=0;i<12;i++){ a[i]=A.row[i]; inv[i]=1u<<i; }
  for(int c=0;c<12;c++){
    int p=-1;
    for(int r2=c;r2<12;r2++) if((a[r2]>>c)&1u){p=r2;break;}
    if(p<0) continue;
    unsigned ta=a[c]; a[c]=a[p]; a[p]=ta;
    unsigned ti=inv[c]; inv[c]=inv[p]; inv[p]=ti;
    for(int r2=0;r2<12;r2++) if(r2!=c && ((a[r2]>>c)&1u)){ a[r2]^=a[c]; inv[r2]^=inv[c]; }
  }
  GF12 R{}; for(int i=0;i<12;i++) R.row[i]=inv[i];
  return R;
}
constexpr unsigned sigma12(unsigned x){ return x ^ (((x>>6)&7u)<<1); }

// independence test in <=6-bit space
constexpr bool indep6(const unsigned* set, int n, unsigned cand){
  unsigned arr[8]{}; int hb[8]{}; int m=0;
  for(int i=0;i<n;i++){
    unsigned y=set[i];
    for(int t2=0;t2<m;t2++) if((y>>hb[t2])&1u) y^=arr[t2];
    if(y){ int h=0; for(int b2=5;b2>=0;b2--) if((y>>b2)&1u){h=b2;break;} arr[m]=y; hb[m]=h; m++; }
  }
  unsigned y=cand;
  for(int t2=0;t2<m;t2++) if((y>>hb[t2])&1u) y^=arr[t2];
  return y!=0u;
}

struct Tab3 {
  unsigned WL8[7][6];    // byte-shifted lane write-basis sigma(L_{p+1} u_i)<<3
  unsigned WZ8[7][64];   // byte-shifted slot write consts sigma(L_{p+1} L_p^-1 z)<<3
  unsigned rm[12];       // measurement parity rows over logical a of L_7
  bool ok;
};

constexpr Tab3 make3(){
  Tab3 T{}; T.ok = true;
  // CNOT-folding recurrences (validated r1/r3)
  GF12 D=gf_id(); for(int q=0;q<12;q++) D=gf_mul(gf_cnot(q),D);
  GF12 C=gf_id(); for(int q=11;q>=0;q--) C=gf_mul(gf_cnot(q),C);
  GF12 Ml[5]{}, Mil[5]{};
  Ml[0]=gf_id(); Mil[0]=gf_id();
  for(int l=0;l<4;l++){ Ml[l+1]=gf_mul(D,Ml[l]); Mil[l+1]=gf_mul(C,Mil[l]); }
  unsigned rfin[12]{};
  for(int q=0;q<12;q++) rfin[q]=Ml[4].row[11-q];

  unsigned V[8][6]{}, R[8][6]{};
  GF12 L[8]{};
  for(int p=0;p<8;p++){
    int l=p>>1;
    bool used[12]={};
    for(int j=0;j<6;j++){
      int qq=(6*p+j)%12; int b=11-qq;
      unsigned v=0;
      for(int i2=0;i2<12;i2++) v |= ((Mil[l].row[i2]>>b)&1u)<<i2;
      V[p][j]=v; R[p][j]=Ml[l].row[b];
      L[p].row[j]=R[p][j];
      used[b]=true;
    }
    int n=6;
    for(int b=0;b<12;b++) if(!used[b]) L[p].row[n++]=Ml[l].row[b];
  }

  // per-transition: re-pick rows 6..8 of L[p+1] within the annihilator span
  // so the lane->bank-pair map of the scattered write is rank 4.
  for(int p=0;p<7;p++){
    GF12 Li=gf_inv(L[p]);
    { GF12 I2=gf_mul(L[p],Li); for(int i2=0;i2<12;i2++) if(I2.row[i2]!=(1u<<i2)) T.ok=false; }
    unsigned u[6]{};
    for(int i2=0;i2<6;i2++) u[i2]=gf_apply(Li,1u<<(6+i2));
    unsigned wrow[6]{}; for(int k=0;k<6;k++) wrow[k]=L[p+1].row[6+k];
    // restrictions to U-space (6-bit functionals)
    unsigned f0=0,qf[3]={0,0,0};
    for(int i2=0;i2<6;i2++){
      f0    |= (unsigned)(__builtin_popcount(L[p+1].row[0]&u[i2])&1)<<i2;
      qf[0] |= (unsigned)(__builtin_popcount(L[p+1].row[1]&u[i2])&1)<<i2;
      qf[1] |= (unsigned)(__builtin_popcount(L[p+1].row[2]&u[i2])&1)<<i2;
      qf[2] |= (unsigned)(__builtin_popcount(L[p+1].row[3]&u[i2])&1)<<i2;
    }
    unsigned s_[6]{};
    for(int k=0;k<6;k++){
      unsigned sr=0;
      for(int i2=0;i2<6;i2++) sr |= (unsigned)(__builtin_popcount(wrow[k]&u[i2])&1)<<i2;
      s_[k]=sr;
    }
    unsigned A[6]{}; int nA=0;           // chosen alpha masks (row-independence in W)
    unsigned B[4]{}; int nB=0;           // E-functional basis (bank-pair rank)
    if(f0){ B[nB++]=f0; }
    unsigned newrow[3]{};
    for(int m=0;m<3;m++){
      unsigned pick=0; bool found=false;
      for(unsigned al=1; al<64 && !found; al++){
        if(!indep6(A,nA,al)) continue;
        unsigned cr=0; for(int k=0;k<6;k++) if((al>>k)&1u) cr^=s_[k];
        unsigned e = qf[m]^cr;
        if(indep6(B,nB,e)){ pick=al; B[nB++]=e; found=true; }
      }
      if(!found){  // fallback: keep rows valid (conflicts tolerated)
        for(unsigned al=1; al<64; al++) if(indep6(A,nA,al)){ pick=al; break; }
      }
      A[nA++]=pick;
      unsigned nr=0; for(int k=0;k<6;k++) if((pick>>k)&1u) nr^=wrow[k];
      newrow[m]=nr;
    }
    // complete rows 9..11 with original annihilator rows
    unsigned fin[6]{newrow[0],newrow[1],newrow[2],0,0,0}; int nf=3;
    for(unsigned k=0;k<6 && nf<6;k++){
      unsigned al=1u<<k;
      if(indep6(A,nA,al)){ A[nA++]=al; fin[nf++]=wrow[k]; }
    }
    if(nf!=6) T.ok=false;
    for(int k=0;k<6;k++) L[p+1].row[6+k]=fin[k];
  }

  // hard invariants (after adjustment)
  for(int p=0;p<8;p++){
    GF12 Li=gf_inv(L[p]);
    GF12 I2=gf_mul(L[p],Li);
    for(int i2=0;i2<12;i2++) if(I2.row[i2]!=(1u<<i2)) T.ok=false;
    for(int j=0;j<6;j++){
      if(gf_apply(L[p],V[p][j])!=(1u<<j)) T.ok=false;
      for(int i2=0;i2<6;i2++){
        int par=__builtin_popcount(R[p][j]&V[p][i2])&1;
        if(par!=((i2==j)?1:0)) T.ok=false;
      }
    }
  }

  // tables
  for(int p=0;p<7;p++){
    GF12 Li=gf_inv(L[p]);
    for(int i2=0;i2<6;i2++){
      unsigned uu=gf_apply(Li,1u<<(6+i2));
      T.WL8[p][i2]=sigma12(gf_apply(L[p+1],uu))<<3;
    }
    for(int z=0;z<64;z++){
      unsigned x=gf_apply(Li,(unsigned)z);
      T.WZ8[p][z]=sigma12(gf_apply(L[p+1],x))<<3;
    }
  }
  // measurement rows vs L_7 logical space
  GF12 L7i=gf_inv(L[7]);
  for(int q=0;q<12;q++){
    unsigned rmv=0;
    for(int j=0;j<12;j++){
      unsigned colj=gf_apply(L7i,1u<<j);
      rmv |= (unsigned)(__builtin_popcount(rfin[q]&colj)&1)<<j;
    }
    T.rm[q]=rmv;
    for(int k2=0;k2<12;k2++){
      unsigned a=gf_apply(L[7],1u<<k2);
      if((__builtin_popcount(rmv&a)&1)!=(__builtin_popcount(rfin[q]&(1u<<k2))&1)) T.ok=false;
    }
  }
  return T;
}

constexpr Tab3 hT3 = make3();
static_assert(hT3.ok, "GF(2) radix-64 table self-check failed");
__constant__ Tab3 cT3 = hT3;

// register slot n_ (0..63): re/im inside float4 Q[32].
// param must NOT be named x/y/z/w (macro member-token capture).
#define SR(n_) (((n_)&1) ? Q[(n_)>>1].z : Q[(n_)>>1].x)
#define SI(n_) (((n_)&1) ? Q[(n_)>>1].w : Q[(n_)>>1].y)

#define GATE(JJ) do { \
    const int _lb = pl + 4*(JJ); \
    const float ar = __uint_as_float((unsigned)__builtin_amdgcn_readlane((int)cur, _lb+0)); \
    const float ai = __uint_as_float((unsigned)__builtin_amdgcn_readlane((int)cur, _lb+1)); \
    const float br = __uint_as_float((unsigned)__builtin_amdgcn_readlane((int)cur, _lb+2)); \
    const float bi = __uint_as_float((unsigned)__builtin_amdgcn_readlane((int)cur, _lb+3)); \
    _Pragma("unroll") \
    for (int s0=0; s0<64; ++s0){ \
      if ((s0 >> (JJ)) & 1) continue; \
      const int s1 = s0 | (1<<(JJ)); \
      const float xr=SR(s0), xi=SI(s0), yr=SR(s1), yi=SI(s1); \
      SR(s0)=fmaf(ar,xr,fmaf(-ai,xi,fmaf(br,yr,-(bi*yi)))); \
      SI(s0)=fmaf(ar,xi,fmaf( ai,xr,fmaf(br,yi,  bi*yr ))); \
      SR(s1)=fmaf(ar,yr,fmaf( ai,yi,fmaf(-br,xr,-(bi*xi)))); \
      SI(s1)=fmaf(ar,yi,fmaf(-ai,yr,fmaf( bi,xr,-(br*xi)))); \
    } \
  } while(0)

__global__ void __launch_bounds__(TPB, 1)
qgen(const float* __restrict__ noise,
     const float* __restrict__ W1, const float* __restrict__ b1,
     const float* __restrict__ W2, const float* __restrict__ b2,
     const float* __restrict__ W3, const float* __restrict__ b3,
     const float* __restrict__ W4, const float* __restrict__ b4,
     float* __restrict__ out)
{
  __shared__ float4 smem[2048];     // exactly 32 KiB -> 5 blocks/CU (LDS-capped)
  float* sf = (float*)smem;

  const int t = threadIdx.x;        // 0..63, one wave per block
  const int b = blockIdx.x;

  // ---- prologue MLP (scratch: gates=floats 0..255, h=256..319, par=320..463) ----
  float nk[12];
  #pragma unroll
  for (int k=0;k<12;++k) nk[k] = noise[b*12+k];     // wave-uniform broadcast loads
  float a1 = b1[t];
  #pragma unroll
  for (int k=0;k<12;++k) a1 = fmaf(nk[k], W1[k*64+t], a1);
  sf[256+t] = tanhf(a1);
  __syncthreads();
  #pragma unroll
  for (int r=0;r<3;++r){
    int j = t + 64*r;
    if (j < 144){
      float a = b2[j];
      #pragma unroll 16
      for (int k=0;k<64;++k) a = fmaf(sf[256+k], W2[k*144+j], a);
      sf[320+j] = a;
    }
  }
  __syncthreads();
  if (t < 48){
    float aa = sf[320+3*t+0]*0.5f, bb = sf[320+3*t+1]*0.5f, c = sf[320+3*t+2]*0.5f;
    float sa,ca,sb,cb,sc2,cc;
    __sincosf(aa,&sa,&ca); __sincosf(bb,&sb,&cb); __sincosf(c,&sc2,&cc);
    float A=cb*ca, B=sb*sa, Cc=sb*ca, Dd=cb*sa;
    // gate g -> pass p=g/6, j=g%6 -> coeff-float base 32p+4j -> float4 slot 8p+j
    smem[8*(t/6) + (t%6)] = make_float4(fmaf(cc,A,  sc2*B),  fmaf(cc,B, -sc2*A),
                                        fmaf(-cc,Cc,-sc2*Dd), fmaf(sc2,Cc,-cc*Dd));
  }
  __syncthreads();
  const unsigned* su = (const unsigned*)smem;
  const unsigned cu0 = su[t], cu1 = su[64+t], cu2 = su[128+t], cu3 = su[192+t];
  __syncthreads();

  // ---- init |0..0>: logical a = L_0 * 0 = 0 -> lane 0, slot 0 ----
  float4 Q[32];
  #pragma unroll
  for (int k=0;k<32;++k) Q[k] = make_float4(0.f,0.f,0.f,0.f);
  if (t==0) Q[0].x = 1.0f;

  const unsigned rq4 = ((unsigned)t<<5) ^ ((unsigned)t & 7u);  // swizzled float4 read base

  // ---- 8 radix-64 passes, zero barriers needed between phases of a pass ----
  #pragma unroll 1
  for (int p=0; p<8; ++p){
    const int ps = p>>1;
    const unsigned cur = (ps==0)?cu0:((ps==1)?cu1:((ps==2)?cu2:cu3));
    const int pl = (p&1)<<5;
    GATE(0); GATE(1); GATE(2); GATE(3); GATE(4); GATE(5);

    if (p==7) break;                       // final state stays in registers
    unsigned lb8 = 0;
    #pragma unroll
    for (int i=0;i<6;++i) lb8 ^= (((unsigned)t>>i)&1u) ? cT3.WL8[p][i] : 0u;
    char* sb = (char*)smem;
    #pragma unroll
    for (int z=0; z<64; ++z)
      *(float2*)(sb + (lb8 ^ cT3.WZ8[p][z])) = make_float2(SR(z), SI(z));
    __syncthreads();                       // 1-wave block: just an LDS drain
    #pragma unroll
    for (int k=0;k<32;++k) Q[k] = smem[rq4 ^ (unsigned)k];   // conflict-free b128
  }

  // ---- measurement from registers: sign = parity(rm & (z | t<<6)) ----
  float pr[64];
  #pragma unroll
  for (int z=0; z<64; ++z){ float xr=SR(z), xi=SI(z); pr[z] = fmaf(xr,xr, xi*xi); }
  float meas[12];
  #pragma unroll
  for (int q=0;q<12;++q){
    float a = 0.f;
    #pragma unroll
    for (int z=0; z<64; ++z){
      if (__builtin_popcount(hT3.rm[q] & (unsigned)z) & 1) a -= pr[z]; else a += pr[z];
    }
    const unsigned ls = ((unsigned)(__popc((hT3.rm[q]>>6) & (unsigned)t) & 1)) << 31;
    a = __uint_as_float(__float_as_uint(a) ^ ls);
    #pragma unroll
    for (int m=1; m<64; m<<=1) a += __shfl_xor(a, m, 64);
    meas[q] = a;                           // all lanes hold the sum
  }

  // ---- epilogue MLP ----
  float a3 = b3[t];
  #pragma unroll
  for (int q=0;q<12;++q) a3 = fmaf(meas[q], W3[q*64+t], a3);
  float h2 = tanhf(a3);
  float p0 = h2*W4[2*t+0], p1 = h2*W4[2*t+1];
  #pragma unroll
  for (int m=1; m<64; m<<=1){ p0 += __shfl_xor(p0,m,64); p1 += __shfl_xor(p1,m,64); }
  if (t==0){ out[2*b+0] = p0 + b4[0]; out[2*b+1] = p1 + b4[1]; }
}

extern "C" void kernel_launch(void* const* d_in, const int* in_sizes, int n_in,
                              void* d_out, int out_size, void* d_ws, size_t ws_size,
                              hipStream_t stream)
{
  const float* noise = (const float*)d_in[0];
  const float* W1 = (const float*)d_in[1];
  const float* b1 = (const float*)d_in[2];
  const float* W2 = (const float*)d_in[3];
  const float* b2 = (const float*)d_in[4];
  const float* W3 = (const float*)d_in[5];
  const float* b3 = (const float*)d_in[6];
  const float* W4 = (const float*)d_in[7];
  const float* b4 = (const float*)d_in[8];
  float* out = (float*)d_out;
  const int batch = in_sizes[0] / NQ;   // 4096
  qgen<<<batch, TPB, 0, stream>>>(noise, W1, b1, W2, b2, W3, b3, W4, b4, out);
}

// Round 6
// 237.318 us; speedup vs baseline: 1.1992x; 1.1992x over previous
//
#include <hip/hip_runtime.h>
#include <math.h>

#define NQ  12
#define TPB 256

// ================= compile-time GF(2) machinery =================
// Fixed physical layout (CNOT-folded storage space, validated r1/r3):
// gate on qubit q in layer l pairs x <-> x^v (v = col b of Minv_l, b=11-q),
// role = parity(r & x) (r = row b of M_l), r_j . v_i = delta_ij.
// IN-PLACE passes: pass p, thread t owns coset addr[z] = B_p t ^ C_p[z],
// C_p[z] = xor of v_j per bits of z. Reads coset, applies 4 gates
// (role_j = parity(M_j & t) ^ z_j, M_j = r_j . B_p), writes back SAME
// addresses -> one barrier per pass, no permutation.
// Conflict-freedom (constructive): float2-index bank-pair residue = x&15.
// B_p[0..3] residues forced to 1,2,4,8; B_p[4..5] residue 0 -> within-wave
// lane->bank-pair map rank 4 -> 4 dwords/bank floor for both b64 reads and
// b64 writes (same addresses).

struct GF12 { unsigned row[12]; };

constexpr GF12 gf_id(){ GF12 m{}; for(int i=0;i<12;i++) m.row[i]=1u<<i; return m; }
constexpr GF12 gf_mul(const GF12&A,const GF12&B){
  GF12 r{};
  for(int i=0;i<12;i++){ unsigned acc=0;
    for(int k=0;k<12;k++) if((A.row[i]>>k)&1u) acc ^= B.row[k];
    r.row[i]=acc; }
  return r;
}
constexpr GF12 gf_cnot(int q){ GF12 m=gf_id(); int c=11-q, t=11-((q+1)%12); m.row[t]^=(1u<<c); return m; }

// incremental GF(2) elimination state (cheap: O(n) per candidate test)
struct Red { unsigned arr[12]; int hb[12]; int n; };
constexpr unsigned red_reduce(const Red& R, unsigned y){
  for(int i=0;i<R.n;i++) if((y>>R.hb[i])&1u) y ^= R.arr[i];
  return y;
}
constexpr bool red_add(Red& R, unsigned cand){
  unsigned y = red_reduce(R, cand);
  if(!y) return false;
  int h=0;
  for(int b2=11;b2>=1;b2--) if((y>>b2)&1u){ h=b2; break; }
  R.arr[R.n]=y; R.hb[R.n]=h; R.n++;
  return true;
}

struct Tab4 {
  unsigned B[12][8];     // lane rep basis per pass (float2-index space)
  unsigned C[12][16];    // slot coset offsets per pass
  unsigned M[12][4];     // role masks (8-bit over t) per gate
  unsigned mq[12];       // measurement lane-sign masks (8-bit over t)
  unsigned uq[12];       // measurement WHT index (4-bit over z)
  bool ok;
};

constexpr Tab4 make4(){
  Tab4 T{}; T.ok=true;
  // v/r construction (validated r1/r3)
  GF12 D=gf_id(); for(int q=0;q<12;q++) D=gf_mul(gf_cnot(q),D);
  GF12 Cm=gf_id(); for(int q=11;q>=0;q--) Cm=gf_mul(gf_cnot(q),Cm);
  unsigned V[12][4]{},R[12][4]{},rfin[12]{};
  GF12 Mm=gf_id(), Mi=gf_id();
  for(int l=0;l<4;l++){
    for(int q=0;q<12;q++){
      int b=11-q; unsigned v=0;
      for(int j=0;j<12;j++) v|=((Mi.row[j]>>b)&1u)<<j;
      V[l*3+q/4][q&3]=v; R[l*3+q/4][q&3]=Mm.row[b];
    }
    Mm=gf_mul(D,Mm); Mi=gf_mul(Cm,Mi);
  }
  for(int q=0;q<12;q++) rfin[q]=Mm.row[11-q];

  for(int p=0;p<12;p++){
    // role identity r_j . v_i = delta_ij
    for(int j=0;j<4;j++) for(int i=0;i<4;i++){
      int par=__builtin_popcount(R[p][j]&V[p][i])&1;
      if(par!=((i==j)?1:0)) T.ok=false;
    }
    Red S{};
    for(int i=0;i<4;i++) if(!red_add(S,V[p][i])) T.ok=false;
    // B[0..3]: residue forced to 1,2,4,8; search high bits for independence
    for(int k=0;k<4;k++){
      unsigned pick=0;
      for(unsigned m=0;m<256 && !pick;m++){
        unsigned x=(1u<<k)|(m<<4);
        if(red_reduce(S,x)) pick=x;
      }
      if(!pick){ T.ok=false; pick=1u<<k; }
      red_add(S,pick); T.B[p][k]=pick;
    }
    // B[4..5]: residue 0
    for(int k=4;k<6;k++){
      unsigned pick=0;
      for(unsigned m=1;m<256 && !pick;m++){
        unsigned x=m<<4;
        if(red_reduce(S,x)) pick=x;
      }
      if(!pick){ T.ok=false; pick=16; }
      red_add(S,pick); T.B[p][k]=pick;
    }
    // B[6..7]: anything completing the basis (wave-id bits, banks irrelevant)
    for(int k=6;k<8;k++){
      unsigned pick=0;
      for(unsigned x=1;x<4096 && !pick;x++){
        if(red_reduce(S,x)) pick=x;
      }
      if(!pick){ T.ok=false; pick=1; }
      red_add(S,pick); T.B[p][k]=pick;
    }
    if(S.n!=12) T.ok=false;
    // slot offsets + role masks
    for(int z=0;z<16;z++){
      unsigned c=0;
      for(int i=0;i<4;i++) if((z>>i)&1) c^=V[p][i];
      T.C[p][z]=c;
    }
    for(int j=0;j<4;j++){
      unsigned m=0;
      for(int i=0;i<8;i++) m|=(unsigned)(__builtin_popcount(R[p][j]&T.B[p][i])&1)<<i;
      T.M[p][j]=m;
    }
  }
  // measurement: sign_q(x)=parity(rfin_q & x), x = B11 t ^ C11[z]
  // WHT over z with characters (-1)^{u.z}: u_i = rfin_q . v_i; lane sign from B11.
  for(int q=0;q<12;q++){
    unsigned u=0,m=0;
    for(int i=0;i<4;i++) u|=(unsigned)(__builtin_popcount(rfin[q]&V[11][i])&1)<<i;
    for(int i=0;i<8;i++) m|=(unsigned)(__builtin_popcount(rfin[q]&T.B[11][i])&1)<<i;
    T.uq[q]=u; T.mq[q]=m;
  }
  return T;
}

constexpr Tab4 hT4 = make4();
static_assert(hT4.ok, "GF(2) in-place table self-check failed");
__constant__ Tab4 cT4 = hT4;

// register slot n_: re/im inside float4 Q[8].
// param must NOT be named x/y/z/w (macro member-token capture, r2 lesson).
#define SR(n_) (((n_)&1) ? Q[(n_)>>1].z : Q[(n_)>>1].x)
#define SI(n_) (((n_)&1) ? Q[(n_)>>1].w : Q[(n_)>>1].y)

// butterfly with per-lane sign folded into ai/br (validated r1)
#define GATE(MM,JJ) do { \
    const int _lb = pl + 4*(JJ); \
    const unsigned _sg = ((unsigned)(__popc((MM) & (unsigned)t) & 1)) << 31; \
    const float ar = __uint_as_float((unsigned)__builtin_amdgcn_readlane((int)cur, _lb+0)); \
    const float ai = __uint_as_float(((unsigned)__builtin_amdgcn_readlane((int)cur, _lb+1)) ^ _sg); \
    const float br = __uint_as_float(((unsigned)__builtin_amdgcn_readlane((int)cur, _lb+2)) ^ _sg); \
    const float bi = __uint_as_float((unsigned)__builtin_amdgcn_readlane((int)cur, _lb+3)); \
    _Pragma("unroll") \
    for (int s0=0; s0<16; ++s0){ \
      if ((s0 >> (JJ)) & 1) continue; \
      const int s1 = s0 | (1<<(JJ)); \
      const float xr=SR(s0), xi=SI(s0), yr=SR(s1), yi=SI(s1); \
      SR(s0)=fmaf(ar,xr,fmaf(-ai,xi,fmaf(br,yr,-(bi*yi)))); \
      SI(s0)=fmaf(ar,xi,fmaf( ai,xr,fmaf(br,yi,  bi*yr ))); \
      SR(s1)=fmaf(ar,yr,fmaf( ai,yi,fmaf(-br,xr,-(bi*xi)))); \
      SI(s1)=fmaf(ar,yi,fmaf(-ai,yr,fmaf( bi,xr,-(br*xi)))); \
    } \
  } while(0)

__global__ void __launch_bounds__(TPB, 5)
qgen(const float* __restrict__ noise,
     const float* __restrict__ W1, const float* __restrict__ b1,
     const float* __restrict__ W2, const float* __restrict__ b2,
     const float* __restrict__ W3, const float* __restrict__ b3,
     const float* __restrict__ W4, const float* __restrict__ b4,
     float* __restrict__ out)
{
  __shared__ float2 s2[4096];              // exactly 32 KiB -> 5 blocks/CU
  float*  sf = (float*)s2;
  float4* s4 = (float4*)s2;

  const int t = threadIdx.x;
  const int b = blockIdx.x;
  const int lane = t & 63;

  // ---- prologue MLP (scratch aliased into state region; r3-validated) ----
  // gates: floats 0..191 | h: 192..255 | par: 256..399 | noise: 400..411
  if (t < 12) sf[400+t] = noise[b*12+t];
  __syncthreads();
  if (t < 64){
    float a = b1[t];
    #pragma unroll
    for (int k=0;k<12;++k) a = fmaf(sf[400+k], W1[k*64+t], a);
    sf[192+t] = tanhf(a);
  }
  __syncthreads();
  if (t < 144){
    float a = b2[t];
    #pragma unroll 16
    for (int j=0;j<64;++j) a = fmaf(sf[192+j], W2[j*144+t], a);
    sf[256+t] = a;
  }
  __syncthreads();
  if (t < 48){
    float aa = sf[256+3*t+0]*0.5f, bb = sf[256+3*t+1]*0.5f, c = sf[256+3*t+2]*0.5f;
    float sa,ca,sb,cb,sc2,cc;
    __sincosf(aa,&sa,&ca); __sincosf(bb,&sb,&cb); __sincosf(c,&sc2,&cc);
    float A=cb*ca, B=sb*sa, Cc=sb*ca, Dd=cb*sa;
    s4[t] = make_float4(fmaf(cc,A,  sc2*B),  fmaf(cc,B, -sc2*A),
                        fmaf(-cc,Cc,-sc2*Dd), fmaf(sc2,Cc,-cc*Dd));
  }
  __syncthreads();
  // pull 48 gate float4s (192 dwords) into 3 per-lane regs (each wave a copy)
  const unsigned* su = (const unsigned*)s2;
  const unsigned cu0 = su[lane], cu1 = su[64+lane], cu2 = su[128+lane];
  __syncthreads();                         // scratch reads done before state writes

  float4 Q[8];
  unsigned addr[16];

  // ---- pass 0: state |0..0> built directly in registers ----
  {
    #pragma unroll
    for (int k=0;k<8;++k) Q[k] = make_float4(0.f,0.f,0.f,0.f);
    if (t==0) Q[0].x = 1.0f;               // x=0: rep(0)=0, C[0][0]=0
    const unsigned cur = cu0; const int pl = 0;
    GATE(cT4.M[0][0],0); GATE(cT4.M[0][1],1); GATE(cT4.M[0][2],2); GATE(cT4.M[0][3],3);
    unsigned rep = 0;
    #pragma unroll
    for (int i=0;i<8;++i) rep ^= (((unsigned)t>>i)&1u) ? cT4.B[0][i] : 0u;
    #pragma unroll
    for (int z=0;z<16;++z) s2[rep ^ cT4.C[0][z]] = make_float2(SR(z), SI(z));
  }
  __syncthreads();

  // ---- passes 1..11: read coset, 4 gates, write back in place ----
  #pragma unroll 1
  for (int p=1; p<12; ++p){
    unsigned rep = 0;
    #pragma unroll
    for (int i=0;i<8;++i) rep ^= (((unsigned)t>>i)&1u) ? cT4.B[p][i] : 0u;
    #pragma unroll
    for (int z=0;z<16;++z) addr[z] = rep ^ cT4.C[p][z];
    #pragma unroll
    for (int z=0;z<16;++z){ float2 v2 = s2[addr[z]]; SR(z)=v2.x; SI(z)=v2.y; }

    const int ps = p>>2;
    const unsigned cur = (ps==0)?cu0:((ps==1)?cu1:cu2);
    const int pl = (p&3)<<4;
    GATE(cT4.M[p][0],0); GATE(cT4.M[p][1],1); GATE(cT4.M[p][2],2); GATE(cT4.M[p][3],3);

    if (p < 11){
      #pragma unroll
      for (int z=0;z<16;++z) s2[addr[z]] = make_float2(SR(z), SI(z));
      __syncthreads();
    }
  }

  // ---- measurement: 16-pt WHT over z (signs are GF(2) characters) ----
  float H[16];
  #pragma unroll
  for (int z=0;z<16;++z) H[z] = fmaf(SR(z),SR(z), SI(z)*SI(z));
  #pragma unroll
  for (int st=1; st<16; st<<=1){
    #pragma unroll
    for (int z=0;z<16;++z){
      if (z & st) continue;
      float a0=H[z], a1=H[z|st];
      H[z]=a0+a1; H[z|st]=a0-a1;
    }
  }
  float acc[12];
  #pragma unroll
  for (int q=0;q<12;++q){
    const unsigned ls = ((unsigned)(__popc(cT4.mq[q] & (unsigned)t) & 1)) << 31;
    acc[q] = __uint_as_float(__float_as_uint(H[cT4.uq[q]]) ^ ls);
  }

  __syncthreads();                         // all pass-11 reads done -> LDS reusable
  const int wv = t >> 6;
  #pragma unroll
  for (int q=0;q<12;++q){
    float v = acc[q];
    #pragma unroll
    for (int off=32; off>0; off>>=1) v += __shfl_down(v, off, 64);
    if (lane==0) sf[wv*12+q] = v;
  }
  __syncthreads();
  if (t < 12) sf[64+t] = sf[t] + sf[12+t] + sf[24+t] + sf[36+t];
  __syncthreads();

  // ---- epilogue MLP on wave 0 (r3-validated) ----
  if (t < 64){
    float a = b3[t];
    #pragma unroll
    for (int k=0;k<12;++k) a = fmaf(sf[64+k], W3[k*64+t], a);
    float h2 = tanhf(a);
    float p0 = h2*W4[2*t+0], p1 = h2*W4[2*t+1];
    #pragma unroll
    for (int off=32; off>0; off>>=1){ p0 += __shfl_down(p0,off,64); p1 += __shfl_down(p1,off,64); }
    if (t==0){ out[2*b+0]=p0+b4[0]; out[2*b+1]=p1+b4[1]; }
  }
}

extern "C" void kernel_launch(void* const* d_in, const int* in_sizes, int n_in,
                              void* d_out, int out_size, void* d_ws, size_t ws_size,
                              hipStream_t stream)
{
  const float* noise = (const float*)d_in[0];
  const float* W1 = (const float*)d_in[1];
  const float* b1 = (const float*)d_in[2];
  const float* W2 = (const float*)d_in[3];
  const float* b2 = (const float*)d_in[4];
  const float* W3 = (const float*)d_in[5];
  const float* b3 = (const float*)d_in[6];
  const float* W4 = (const float*)d_in[7];
  const float* b4 = (const float*)d_in[8];
  float* out = (float*)d_out;
  const int batch = in_sizes[0] / NQ;   // 4096
  qgen<<<batch, TPB, 0, stream>>>(noise, W1, b1, W2, b2, W3, b3, W4, b4, out);
}